// Round 5
// baseline (315.684 us; speedup 1.0000x reference)
//
#include <hip/hip_runtime.h>
#include <stdint.h>

#define E_NUM 8
#define CAP 8192
#define NTOK 32768
#define CDIM 384
#define DFF 1536
#define CNT_PAD 64  // ints between counters -> 256B, separate cache lines

typedef unsigned short u16;
typedef __attribute__((ext_vector_type(8))) short short8;
typedef __attribute__((ext_vector_type(4))) float f32x4;

__device__ inline u16 f2bf(float f) {
    uint32_t u = __builtin_bit_cast(uint32_t, f);
    u += 0x7fffu + ((u >> 16) & 1u);
    return (u16)(u >> 16);
}

__device__ inline void gload_lds16(const void* g, void* l) {
    __builtin_amdgcn_global_load_lds(
        (const __attribute__((address_space(1))) void*)(uintptr_t)g,
        (__attribute__((address_space(3))) void*)(uint32_t)(uintptr_t)l,
        16, 0, 0);
}

// DPP row-rotate reduction -> halves; finish with readlane(0)+readlane(32).
__device__ inline float rsum_to_halves(float v) {
    int s;
    s = __builtin_bit_cast(int, v);
    v += __builtin_bit_cast(float, __builtin_amdgcn_update_dpp(0, s, 0x121, 0xF, 0xF, false));
    s = __builtin_bit_cast(int, v);
    v += __builtin_bit_cast(float, __builtin_amdgcn_update_dpp(0, s, 0x122, 0xF, 0xF, false));
    s = __builtin_bit_cast(int, v);
    v += __builtin_bit_cast(float, __builtin_amdgcn_update_dpp(0, s, 0x124, 0xF, 0xF, false));
    s = __builtin_bit_cast(int, v);
    v += __builtin_bit_cast(float, __builtin_amdgcn_update_dpp(0, s, 0x128, 0xF, 0xF, false));
    s = __builtin_bit_cast(int, v);
    v += __builtin_bit_cast(float, __builtin_amdgcn_ds_swizzle(s, 0x401F));
    return v;
}

__device__ inline float lane_total(float v) {
    int s = __builtin_bit_cast(int, v);
    return __builtin_bit_cast(float, __builtin_amdgcn_readlane(s, 0)) +
           __builtin_bit_cast(float, __builtin_amdgcn_readlane(s, 32));
}

// Inline packed-row prefix (replaces offsets_kernel): 8 L2-hot scalar loads.
__device__ inline void expert_span(const int* __restrict__ cnt, int e,
                                   int& base, int& n_e) {
    base = 0; n_e = 0;
#pragma unroll
    for (int i = 0; i < E_NUM; ++i) {
        int n = min(cnt[i * CNT_PAD], CAP);
        if (i < e) base += (n + 127) & ~127;
        else if (i == e) n_e = n;
    }
}

// ---------------- routing + fused list build + x->bf16 emit ----------------
// R6: build_lists fused (ballot + 1 atomic per expert per block).
// R7: also emits Xbf (token-order bf16 x) — the rows are already in registers,
// so gather_kernel is deleted; FFN1 gathers rows via list indirection.
__global__ __launch_bounds__(256, 1) void routing_kernel(
    const float* __restrict__ x, const float* __restrict__ noise,
    const float* __restrict__ w_route, const float* __restrict__ b_route,
    const float* __restrict__ w_noise, const float* __restrict__ b_noise,
    int* __restrict__ cnt, int* __restrict__ list, float* __restrict__ gate,
    u16* __restrict__ xbf)
{
    __shared__ int s_top1[16];
    int lane = threadIdx.x & 63, w = threadIdx.x >> 6;
    float4 wr4[12], wn4[12];
#pragma unroll
    for (int i = 0; i < 6; ++i) {
        const float4* pr = (const float4*)(w_route + (size_t)(lane + 64 * i) * 8);
        const float4* pn = (const float4*)(w_noise + (size_t)(lane + 64 * i) * 8);
        wr4[2 * i] = pr[0]; wr4[2 * i + 1] = pr[1];
        wn4[2 * i] = pn[0]; wn4[2 * i + 1] = pn[1];
    }
    float br[E_NUM], bn[E_NUM];
#pragma unroll
    for (int e = 0; e < E_NUM; ++e) { br[e] = b_route[e]; bn[e] = b_noise[e]; }

    int tbase = blockIdx.x * 16 + w * 4;
#pragma unroll
    for (int tt = 0; tt < 4; ++tt) {
        int t = tbase + tt;
        const float* xr = x + (size_t)t * CDIM;
        float xv[6];
#pragma unroll
        for (int i = 0; i < 6; ++i) xv[i] = xr[lane + i * 64];
        // emit bf16 row (coalesced 128B per instr)
        u16* xb = xbf + (size_t)t * CDIM;
#pragma unroll
        for (int i = 0; i < 6; ++i) xb[lane + i * 64] = f2bf(xv[i]);
        float ar[E_NUM], an[E_NUM];
#pragma unroll
        for (int e = 0; e < E_NUM; ++e) { ar[e] = 0.f; an[e] = 0.f; }
#pragma unroll
        for (int i = 0; i < 6; ++i) {
            float4 r0 = wr4[2 * i], r1 = wr4[2 * i + 1];
            float4 n0 = wn4[2 * i], n1 = wn4[2 * i + 1];
            float xi = xv[i];
            ar[0] += xi * r0.x; ar[1] += xi * r0.y; ar[2] += xi * r0.z; ar[3] += xi * r0.w;
            ar[4] += xi * r1.x; ar[5] += xi * r1.y; ar[6] += xi * r1.z; ar[7] += xi * r1.w;
            an[0] += xi * n0.x; an[1] += xi * n0.y; an[2] += xi * n0.z; an[3] += xi * n0.w;
            an[4] += xi * n1.x; an[5] += xi * n1.y; an[6] += xi * n1.z; an[7] += xi * n1.w;
        }
        float nz[E_NUM];
        const float* np = noise + (size_t)t * E_NUM;
#pragma unroll
        for (int e = 0; e < E_NUM; ++e) {
            float sr = lane_total(rsum_to_halves(ar[e])) + br[e];
            float sn = lane_total(rsum_to_halves(an[e])) + bn[e];
            float sp = fmaxf(sn, 0.f) + __logf(1.f + __expf(-fabsf(sn)));
            nz[e] = sr + np[e] * sp;
        }
        float v1 = -1e30f; int i1 = 0;
#pragma unroll
        for (int e = 0; e < E_NUM; ++e) if (nz[e] > v1) { v1 = nz[e]; i1 = e; }
        float v2 = -1e30f;
#pragma unroll
        for (int e = 0; e < E_NUM; ++e) if (e != i1 && nz[e] > v2) v2 = nz[e];
        if (lane == 0) {
            gate[t] = 1.f / (1.f + __expf(v2 - v1));
            s_top1[w * 4 + tt] = i1;
        }
    }
    __syncthreads();
    if (w == 0) {
        int tok = blockIdx.x * 16 + lane;
        int e1 = (lane < 16) ? s_top1[lane] : -1;
#pragma unroll
        for (int e = 0; e < E_NUM; ++e) {
            unsigned long long m = __ballot(e1 == e);
            if (m == 0) continue;
            int c = __popcll(m);
            int leader = __ffsll((long long)m) - 1;
            int basec = 0;
            if (lane == leader) basec = atomicAdd(&cnt[e * CNT_PAD], c);
            basec = __shfl(basec, leader);
            if (e1 == e) {
                int pos = basec + __popcll(m & ((1ull << lane) - 1ull));
                if (pos < CAP) list[e * CAP + pos] = tok;
            }
        }
    }
}

// ------------- merged transpose + fp32->bf16 for BOTH weight tensors -------------
__global__ __launch_bounds__(256) void transpose_cvt_kernel(
    const float* __restrict__ w1, u16* __restrict__ W1t,
    const float* __restrict__ w2, u16* __restrict__ W2t)
{
    __shared__ float tile[32][33];
    int z = blockIdx.z;
    const float* in; u16* out; int R, S, r0, c0;
    if (z < E_NUM) {
        in = w1 + (size_t)z * CDIM * DFF;  out = W1t + (size_t)z * CDIM * DFF;
        R = CDIM; S = DFF;
        c0 = blockIdx.x * 32; r0 = blockIdx.y * 32;
    } else {
        in = w2 + (size_t)(z - E_NUM) * DFF * CDIM;
        out = W2t + (size_t)(z - E_NUM) * DFF * CDIM;
        R = DFF; S = CDIM;
        r0 = blockIdx.x * 32; c0 = blockIdx.y * 32;
    }
    int tx = threadIdx.x, ty = threadIdx.y;
#pragma unroll
    for (int i = ty; i < 32; i += 8)
        tile[i][tx] = in[(size_t)(r0 + i) * S + (c0 + tx)];
    __syncthreads();
#pragma unroll
    for (int i = ty; i < 32; i += 8)
        out[(size_t)(c0 + i) * R + (r0 + tx)] = f2bf(tile[tx][i]);
}

// ------------- bf16 MFMA GEMM, 128x128 tile, BK=64, XCD swizzle, XOR-swizzled LDS.
// R6: dbuf LDS + issue-early counted-vmcnt pipeline with raw s_barrier.
//     (R3 post-mortem: neutral vs R0 sync-drain — kept, costs nothing.)
// R7: FFN1 A-rows gathered from token-order Xbf via s_tok (gather kernel gone;
//     pad rows -> zeroed dummy row NTOK, numerically == old zero-padded Xg);
//     FFN1 epilogue LDS-bounced: u16 frag writes -> As LDS (row-XOR swizzle)
//     -> coalesced dwordx4 stores (was 64x 2-byte scattered stores/thread).
template <int KD, int ND, bool FFN1>
__global__ __launch_bounds__(256, 2) void gemm_kernel(
    const u16* __restrict__ A, const u16* __restrict__ Bt,
    const float* __restrict__ bias, u16* __restrict__ H, float* __restrict__ Out,
    const int* __restrict__ cnt, const int* __restrict__ list,
    const float* __restrict__ gate)
{
    constexpr int NT = ND / 128;
    int bid = blockIdx.x;
    int xcd = bid & 7, slot = bid >> 3;
    int n_idx = slot % NT;
    int mglob = xcd + 8 * (slot / NT);     // 0..511
    int e = mglob >> 6;
    int m0 = (mglob & 63) * 128;
    int base, n_e;
    expert_span(cnt, e, base, n_e);
    int pad_e = (n_e + 127) & ~127;
    if (m0 >= pad_e) return;
    const u16* Be = Bt + ((size_t)e * ND + (size_t)n_idx * 128) * KD;

    __shared__ __align__(16) u16 As[2][128 * 64];
    __shared__ __align__(16) u16 Bs[2][128 * 64];
    __shared__ int s_tok[128];

    int tid = threadIdx.x;
    int w = tid >> 6, lane = tid & 63;
    int quad = lane >> 4, l15 = lane & 15;
    int wr = w & 1, wc = w >> 1;

    int srow = tid >> 3;
    int gcol = ((tid & 7) ^ ((tid >> 3) & 7)) * 8;

    if (FFN1) {
        if (tid < 128) {
            int rr = m0 + tid;
            s_tok[tid] = (rr < n_e) ? list[(size_t)e * CAP + rr] : NTOK;
        }
        __syncthreads();
    }
    const u16* Arow[4];
#pragma unroll
    for (int i = 0; i < 4; ++i) {
        int row = i * 32 + srow;
        if (FFN1) Arow[i] = A + (size_t)s_tok[row] * KD;
        else      Arow[i] = A + (size_t)(base + m0 + row) * KD;
    }

    auto stage = [&](int buf, int kb) {
#pragma unroll
        for (int i = 0; i < 4; ++i) {
            gload_lds16(Arow[i] + kb * 64 + gcol, &As[buf][i * 2048 + tid * 8]);
            gload_lds16(Be + (size_t)(i * 32 + srow) * KD + kb * 64 + gcol,
                        &Bs[buf][i * 2048 + tid * 8]);
        }
    };

    f32x4 acc[4][4];
    f32x4 zero = {0.f, 0.f, 0.f, 0.f};
#pragma unroll
    for (int a = 0; a < 4; ++a)
#pragma unroll
        for (int b = 0; b < 4; ++b) acc[a][b] = zero;

    constexpr int NK = KD / 64;
    stage(0, 0);
#pragma unroll 2
    for (int kb = 0; kb < NK; ++kb) {
        const int cur = kb & 1;
        if (kb + 1 < NK) {
            stage(cur ^ 1, kb + 1);                     // issue next tile early
            asm volatile("s_waitcnt vmcnt(8)" ::: "memory");  // wait CURRENT 8 only
        } else {
            asm volatile("s_waitcnt vmcnt(0)" ::: "memory");
        }
        __builtin_amdgcn_s_barrier();
        __builtin_amdgcn_sched_barrier(0);
#pragma unroll
        for (int h = 0; h < 2; ++h) {
            int pga = (((h * 4 + quad) ^ (l15 & 7))) * 8;  // lane-constant per h
            short8 af[4], bf[4];
#pragma unroll
            for (int t = 0; t < 4; ++t) {
                af[t] = *(const short8*)&As[cur][(wr * 64 + t * 16 + l15) * 64 + pga];
                bf[t] = *(const short8*)&Bs[cur][(wc * 64 + t * 16 + l15) * 64 + pga];
            }
#pragma unroll
            for (int mt = 0; mt < 4; ++mt)
#pragma unroll
                for (int nt = 0; nt < 4; ++nt)
                    acc[mt][nt] = __builtin_amdgcn_mfma_f32_16x16x32_bf16(
                        af[mt], bf[nt], acc[mt][nt], 0, 0, 0);
        }
        __builtin_amdgcn_sched_barrier(0);
        __builtin_amdgcn_s_barrier();
        __builtin_amdgcn_sched_barrier(0);
    }

    int n0 = n_idx * 128;
    if (FFN1) {
        // --- LDS-bounce epilogue: frags -> swizzled LDS -> coalesced 16B stores
        u16* Hs = (u16*)&As[0][0];   // 32 KB (both dbuf halves), done with K-loop
#pragma unroll
        for (int mt = 0; mt < 4; ++mt) {
            int rowL = wr * 64 + mt * 16 + quad * 4;
#pragma unroll
            for (int nt = 0; nt < 4; ++nt) {
                int colL = wc * 64 + nt * 16 + l15;
                float b = bias[(size_t)e * ND + n0 + colL];
#pragma unroll
                for (int r = 0; r < 4; ++r) {
                    float v = acc[mt][nt][r] + b;
                    v = fmaxf(v, 0.f);
                    int row = rowL + r;
                    Hs[row * 128 + (colL ^ ((row & 7) << 3))] = f2bf(v * v);
                }
            }
        }
        __syncthreads();
        u16* He = H + (size_t)(base + m0) * ND + n0;
#pragma unroll
        for (int j = 0; j < 8; ++j) {
            int idx = tid + j * 256;          // 16B units of the 32KB tile
            int row = idx >> 4;
            int c8 = (idx & 15) * 8;          // u16 col offset, 8-aligned
            *(f32x4*)(He + (size_t)row * ND + c8) =
                *(const f32x4*)(Hs + row * 128 + (c8 ^ ((row & 7) << 3)));
        }
    } else {
#pragma unroll
        for (int mt = 0; mt < 4; ++mt) {
            int rowL = wr * 64 + mt * 16 + quad * 4;
#pragma unroll
            for (int r = 0; r < 4; ++r) {
                int rr = m0 + rowL + r;
                if (rr < n_e) {
                    int tok = list[(size_t)e * CAP + rr];
                    float g = gate[tok];
#pragma unroll
                    for (int nt = 0; nt < 4; ++nt) {
                        int col = n0 + wc * 64 + nt * 16 + l15;
                        float v = acc[mt][nt][r] + bias[(size_t)e * ND + col];
                        Out[(size_t)tok * CDIM + col] = v * g;
                    }
                }
            }
        }
    }
}

extern "C" void kernel_launch(void* const* d_in, const int* in_sizes, int n_in,
                              void* d_out, int out_size, void* d_ws, size_t ws_size,
                              hipStream_t stream)
{
    const float* x       = (const float*)d_in[0];
    const float* noise   = (const float*)d_in[1];
    const float* w_route = (const float*)d_in[2];
    const float* b_route = (const float*)d_in[3];
    const float* w_noise = (const float*)d_in[4];
    const float* b_noise = (const float*)d_in[5];
    const float* w1      = (const float*)d_in[6];
    const float* b1      = (const float*)d_in[7];
    const float* w2      = (const float*)d_in[8];
    const float* b2      = (const float*)d_in[9];
    float* out = (float*)d_out;

    char* ws = (char*)d_ws;
    size_t off = 0;
    auto alloc = [&](size_t bytes) {
        char* p = ws + off;
        off += (bytes + 255) & ~(size_t)255;
        return p;
    };
    int*   cnt  = (int*)alloc((size_t)E_NUM * CNT_PAD * sizeof(int));
    int*   list = (int*)alloc((size_t)E_NUM * CAP * sizeof(int));
    float* gate = (float*)alloc((size_t)NTOK * sizeof(float));
    u16*   W1t  = (u16*)alloc((size_t)E_NUM * DFF * CDIM * 2);
    u16*   W2t  = (u16*)alloc((size_t)E_NUM * CDIM * DFF * 2);

    u16* Xbf = (u16*)alloc((size_t)(NTOK + 1) * CDIM * 2);  // +1 zero dummy row
    size_t rows = NTOK + E_NUM * 128;  // packed-row bound
    u16* Hb = (u16*)alloc(rows * DFF * 2);

    hipMemsetAsync(cnt, 0, (size_t)E_NUM * CNT_PAD * sizeof(int), stream);
    hipMemsetAsync(Xbf + (size_t)NTOK * CDIM, 0, CDIM * 2, stream);  // dummy row

    routing_kernel<<<NTOK / 16, 256, 0, stream>>>(x, noise, w_route, b_route,
                                                  w_noise, b_noise, cnt, list, gate, Xbf);
    transpose_cvt_kernel<<<dim3(48, 12, 16), dim3(32, 8), 0, stream>>>(w1, W1t, w2, W2t);

    gemm_kernel<CDIM, DFF, true><<<dim3((DFF / 128) * 512), 256, 0, stream>>>(
        Xbf, W1t, b1, Hb, nullptr, cnt, list, nullptr);
    gemm_kernel<DFF, CDIM, false><<<dim3((CDIM / 128) * 512), 256, 0, stream>>>(
        Hb, W2t, b2, nullptr, out, cnt, list, gate);
}

// Round 8
// 305.045 us; speedup vs baseline: 1.0349x; 1.0349x over previous
//
#include <hip/hip_runtime.h>
#include <stdint.h>

#define E_NUM 8
#define CAP 8192
#define NTOK 32768
#define CDIM 384
#define DFF 1536
#define CNT_PAD 64  // ints between counters -> 256B, separate cache lines

typedef unsigned short u16;
typedef __attribute__((ext_vector_type(8))) short short8;
typedef __attribute__((ext_vector_type(4))) float f32x4;

__device__ inline u16 f2bf(float f) {
    uint32_t u = __builtin_bit_cast(uint32_t, f);
    u += 0x7fffu + ((u >> 16) & 1u);
    return (u16)(u >> 16);
}

__device__ inline void gload_lds16(const void* g, void* l) {
    __builtin_amdgcn_global_load_lds(
        (const __attribute__((address_space(1))) void*)(uintptr_t)g,
        (__attribute__((address_space(3))) void*)(uint32_t)(uintptr_t)l,
        16, 0, 0);
}

// Inline packed-row prefix (replaces offsets_kernel): 8 L2-hot scalar loads.
__device__ inline void expert_span(const int* __restrict__ cnt, int e,
                                   int& base, int& n_e) {
    base = 0; n_e = 0;
#pragma unroll
    for (int i = 0; i < E_NUM; ++i) {
        int n = min(cnt[i * CNT_PAD], CAP);
        if (i < e) base += (n + 127) & ~127;
        else if (i == e) n_e = n;
    }
}

// ---------------- routing v3: thread-per-token, zero cross-lane reductions ----
// R5 post-mortem: wave-per-token + DPP chains = ~325 VALU issue-slots/token
// (16 serial reduce chains, 32 readlanes, 64-lane-redundant tail, weight quads
// re-fetched because VGPR=72 < the 96-float working set) -> 85 us, VALUBusy 30%.
// v3: block = 64 tokens x 4 k-segment WAVES. Weights are indexed only by
// (chunk, seg=readfirstlane(wid), j) -> provably wave-uniform -> s_load via the
// scalar pipe (no VALU slots, no VGPR pressure). x staged to LDS coalesced per
// 64-k chunk (emitting bf16 Xbf on the way); each thread dots ITS token from
// LDS: 16 independent FMA chains, ILP covers VALU latency. Per-wave partials
// combine via an LDS overlay; wave 0 runs the tail with one token per lane
// (softplus/selection/gate/ballot cost amortized 64x).
#define RT_TOK 64   // tokens per block
#define RT_KC 64    // k-chunk staged per round
#define RT_XS 68    // LDS row stride, floats (68*4=272 B, 16B-aligned)

__global__ __launch_bounds__(256, 4) void routing_kernel(
    const float* __restrict__ x, const float* __restrict__ noise,
    const float* __restrict__ w_route, const float* __restrict__ b_route,
    const float* __restrict__ w_noise, const float* __restrict__ b_noise,
    int* __restrict__ cnt, int* __restrict__ list, float* __restrict__ gate,
    u16* __restrict__ xbf)
{
    __shared__ float xs[RT_TOK * RT_XS];       // 17408 B; partials overlay at end
    int tid = threadIdx.x;
    int lane = tid & 63;
    int seg = __builtin_amdgcn_readfirstlane(tid >> 6);  // SGPR -> uniform k-range
    int tok = tid & 63;
    int t0 = blockIdx.x * RT_TOK;

    int srow = tid >> 4;          // 0..15 (staging row within pass)
    int scol = (tid & 15) * 4;    // float col within chunk

    float ar[E_NUM], an[E_NUM];
#pragma unroll
    for (int e = 0; e < E_NUM; ++e) { ar[e] = 0.f; an[e] = 0.f; }

    for (int c = 0; c < CDIM / RT_KC; ++c) {
        __syncthreads();   // previous chunk fully consumed
#pragma unroll
        for (int p = 0; p < 4; ++p) {
            int row = p * 16 + srow;
            float4 v = *(const float4*)(x + (size_t)(t0 + row) * CDIM + c * RT_KC + scol);
            *(float4*)&xs[row * RT_XS + scol] = v;
            uint2 b;
            b.x = (uint32_t)f2bf(v.x) | ((uint32_t)f2bf(v.y) << 16);
            b.y = (uint32_t)f2bf(v.z) | ((uint32_t)f2bf(v.w) << 16);
            *(uint2*)(xbf + (size_t)(t0 + row) * CDIM + c * RT_KC + scol) = b;
        }
        __syncthreads();
#pragma unroll
        for (int q = 0; q < 4; ++q) {
            float4 xq = *(const float4*)&xs[tok * RT_XS + seg * 16 + q * 4];
            int kb = c * RT_KC + seg * 16 + q * 4;   // wave-uniform
#pragma unroll
            for (int jj = 0; jj < 4; ++jj) {
                const float* wrk = w_route + (size_t)(kb + jj) * E_NUM;
                const float* wnk = w_noise + (size_t)(kb + jj) * E_NUM;
                float4 wa = *(const float4*)wrk, wb = *(const float4*)(wrk + 4);
                float4 na = *(const float4*)wnk, nb = *(const float4*)(wnk + 4);
                float xk = (jj == 0) ? xq.x : (jj == 1) ? xq.y : (jj == 2) ? xq.z : xq.w;
                ar[0] += xk * wa.x; ar[1] += xk * wa.y; ar[2] += xk * wa.z; ar[3] += xk * wa.w;
                ar[4] += xk * wb.x; ar[5] += xk * wb.y; ar[6] += xk * wb.z; ar[7] += xk * wb.w;
                an[0] += xk * na.x; an[1] += xk * na.y; an[2] += xk * na.z; an[3] += xk * na.w;
                an[4] += xk * nb.x; an[5] += xk * nb.y; an[6] += xk * nb.z; an[7] += xk * nb.w;
            }
        }
    }
    // ---- combine 4 k-segment partials via LDS overlay (16 KB <= 17.4 KB) ----
    __syncthreads();
    float* part = xs;
    float* pp = part + (size_t)(seg * 64 + tok) * 16;
    *(f32x4*)&pp[0]  = (f32x4){ar[0], ar[1], ar[2], ar[3]};
    *(f32x4*)&pp[4]  = (f32x4){ar[4], ar[5], ar[6], ar[7]};
    *(f32x4*)&pp[8]  = (f32x4){an[0], an[1], an[2], an[3]};
    *(f32x4*)&pp[12] = (f32x4){an[4], an[5], an[6], an[7]};
    __syncthreads();
    if (seg == 0) {
        int t = t0 + lane;
        float sr[E_NUM], sn[E_NUM];
#pragma unroll
        for (int e = 0; e < E_NUM; ++e) { sr[e] = b_route[e]; sn[e] = b_noise[e]; }
#pragma unroll
        for (int s = 0; s < 4; ++s) {
            const float* q = part + (size_t)(s * 64 + lane) * 16;
#pragma unroll
            for (int e = 0; e < E_NUM; ++e) { sr[e] += q[e]; sn[e] += q[8 + e]; }
        }
        float nz[E_NUM];
        const float* np = noise + (size_t)t * E_NUM;
#pragma unroll
        for (int e = 0; e < E_NUM; ++e) {
            float s = sn[e];
            float sp = fmaxf(s, 0.f) + __logf(1.f + __expf(-fabsf(s)));
            nz[e] = sr[e] + np[e] * sp;
        }
        float v1 = -1e30f; int i1 = 0;
#pragma unroll
        for (int e = 0; e < E_NUM; ++e) if (nz[e] > v1) { v1 = nz[e]; i1 = e; }
        float v2 = -1e30f;
#pragma unroll
        for (int e = 0; e < E_NUM; ++e) if (e != i1 && nz[e] > v2) v2 = nz[e];
        gate[t] = 1.f / (1.f + __expf(v2 - v1));
#pragma unroll
        for (int e = 0; e < E_NUM; ++e) {
            unsigned long long m = __ballot(i1 == e);
            if (m == 0) continue;
            int cnum = __popcll(m);
            int leader = __ffsll((long long)m) - 1;
            int basec = 0;
            if (lane == leader) basec = atomicAdd(&cnt[e * CNT_PAD], cnum);
            basec = __shfl(basec, leader);
            if (i1 == e) {
                int pos = basec + __popcll(m & ((1ull << lane) - 1ull));
                if (pos < CAP) list[e * CAP + pos] = t;
            }
        }
    }
}

// ------------- merged transpose + fp32->bf16 for BOTH weight tensors -------------
__global__ __launch_bounds__(256) void transpose_cvt_kernel(
    const float* __restrict__ w1, u16* __restrict__ W1t,
    const float* __restrict__ w2, u16* __restrict__ W2t)
{
    __shared__ float tile[32][33];
    int z = blockIdx.z;
    const float* in; u16* out; int R, S, r0, c0;
    if (z < E_NUM) {
        in = w1 + (size_t)z * CDIM * DFF;  out = W1t + (size_t)z * CDIM * DFF;
        R = CDIM; S = DFF;
        c0 = blockIdx.x * 32; r0 = blockIdx.y * 32;
    } else {
        in = w2 + (size_t)(z - E_NUM) * DFF * CDIM;
        out = W2t + (size_t)(z - E_NUM) * DFF * CDIM;
        R = DFF; S = CDIM;
        r0 = blockIdx.x * 32; c0 = blockIdx.y * 32;
    }
    int tx = threadIdx.x, ty = threadIdx.y;
#pragma unroll
    for (int i = ty; i < 32; i += 8)
        tile[i][tx] = in[(size_t)(r0 + i) * S + (c0 + tx)];
    __syncthreads();
#pragma unroll
    for (int i = ty; i < 32; i += 8)
        out[(size_t)(c0 + i) * R + (r0 + tx)] = f2bf(tile[tx][i]);
}

// ------------- bf16 MFMA GEMM, 128x128 tile, BK=64, XCD swizzle, XOR-swizzled LDS.
// R6: dbuf LDS + issue-early counted-vmcnt pipeline with raw s_barrier.
// R7: FFN1 A-rows gathered from token-order Xbf via s_tok; FFN1 epilogue
//     LDS-bounced to coalesced dwordx4 stores.
template <int KD, int ND, bool FFN1>
__global__ __launch_bounds__(256, 2) void gemm_kernel(
    const u16* __restrict__ A, const u16* __restrict__ Bt,
    const float* __restrict__ bias, u16* __restrict__ H, float* __restrict__ Out,
    const int* __restrict__ cnt, const int* __restrict__ list,
    const float* __restrict__ gate)
{
    constexpr int NT = ND / 128;
    int bid = blockIdx.x;
    int xcd = bid & 7, slot = bid >> 3;
    int n_idx = slot % NT;
    int mglob = xcd + 8 * (slot / NT);     // 0..511
    int e = mglob >> 6;
    int m0 = (mglob & 63) * 128;
    int base, n_e;
    expert_span(cnt, e, base, n_e);
    int pad_e = (n_e + 127) & ~127;
    if (m0 >= pad_e) return;
    const u16* Be = Bt + ((size_t)e * ND + (size_t)n_idx * 128) * KD;

    __shared__ __align__(16) u16 As[2][128 * 64];
    __shared__ __align__(16) u16 Bs[2][128 * 64];
    __shared__ int s_tok[128];

    int tid = threadIdx.x;
    int w = tid >> 6, lane = tid & 63;
    int quad = lane >> 4, l15 = lane & 15;
    int wr = w & 1, wc = w >> 1;

    int srow = tid >> 3;
    int gcol = ((tid & 7) ^ ((tid >> 3) & 7)) * 8;

    if (FFN1) {
        if (tid < 128) {
            int rr = m0 + tid;
            s_tok[tid] = (rr < n_e) ? list[(size_t)e * CAP + rr] : NTOK;
        }
        __syncthreads();
    }
    const u16* Arow[4];
#pragma unroll
    for (int i = 0; i < 4; ++i) {
        int row = i * 32 + srow;
        if (FFN1) Arow[i] = A + (size_t)s_tok[row] * KD;
        else      Arow[i] = A + (size_t)(base + m0 + row) * KD;
    }

    auto stage = [&](int buf, int kb) {
#pragma unroll
        for (int i = 0; i < 4; ++i) {
            gload_lds16(Arow[i] + kb * 64 + gcol, &As[buf][i * 2048 + tid * 8]);
            gload_lds16(Be + (size_t)(i * 32 + srow) * KD + kb * 64 + gcol,
                        &Bs[buf][i * 2048 + tid * 8]);
        }
    };

    f32x4 acc[4][4];
    f32x4 zero = {0.f, 0.f, 0.f, 0.f};
#pragma unroll
    for (int a = 0; a < 4; ++a)
#pragma unroll
        for (int b = 0; b < 4; ++b) acc[a][b] = zero;

    constexpr int NK = KD / 64;
    stage(0, 0);
#pragma unroll 2
    for (int kb = 0; kb < NK; ++kb) {
        const int cur = kb & 1;
        if (kb + 1 < NK) {
            stage(cur ^ 1, kb + 1);                     // issue next tile early
            asm volatile("s_waitcnt vmcnt(8)" ::: "memory");  // wait CURRENT 8 only
        } else {
            asm volatile("s_waitcnt vmcnt(0)" ::: "memory");
        }
        __builtin_amdgcn_s_barrier();
        __builtin_amdgcn_sched_barrier(0);
#pragma unroll
        for (int h = 0; h < 2; ++h) {
            int pga = (((h * 4 + quad) ^ (l15 & 7))) * 8;  // lane-constant per h
            short8 af[4], bf[4];
#pragma unroll
            for (int t = 0; t < 4; ++t) {
                af[t] = *(const short8*)&As[cur][(wr * 64 + t * 16 + l15) * 64 + pga];
                bf[t] = *(const short8*)&Bs[cur][(wc * 64 + t * 16 + l15) * 64 + pga];
            }
#pragma unroll
            for (int mt = 0; mt < 4; ++mt)
#pragma unroll
                for (int nt = 0; nt < 4; ++nt)
                    acc[mt][nt] = __builtin_amdgcn_mfma_f32_16x16x32_bf16(
                        af[mt], bf[nt], acc[mt][nt], 0, 0, 0);
        }
        __builtin_amdgcn_sched_barrier(0);
        __builtin_amdgcn_s_barrier();
        __builtin_amdgcn_sched_barrier(0);
    }

    int n0 = n_idx * 128;
    if (FFN1) {
        // --- LDS-bounce epilogue: frags -> swizzled LDS -> coalesced 16B stores
        u16* Hs = (u16*)&As[0][0];   // 32 KB (both dbuf halves), done with K-loop
#pragma unroll
        for (int mt = 0; mt < 4; ++mt) {
            int rowL = wr * 64 + mt * 16 + quad * 4;
#pragma unroll
            for (int nt = 0; nt < 4; ++nt) {
                int colL = wc * 64 + nt * 16 + l15;
                float b = bias[(size_t)e * ND + n0 + colL];
#pragma unroll
                for (int r = 0; r < 4; ++r) {
                    float v = acc[mt][nt][r] + b;
                    v = fmaxf(v, 0.f);
                    int row = rowL + r;
                    Hs[row * 128 + (colL ^ ((row & 7) << 3))] = f2bf(v * v);
                }
            }
        }
        __syncthreads();
        u16* He = H + (size_t)(base + m0) * ND + n0;
#pragma unroll
        for (int j = 0; j < 8; ++j) {
            int idx = tid + j * 256;          // 16B units of the 32KB tile
            int row = idx >> 4;
            int c8 = (idx & 15) * 8;          // u16 col offset, 8-aligned
            *(f32x4*)(He + (size_t)row * ND + c8) =
                *(const f32x4*)(Hs + row * 128 + (c8 ^ ((row & 7) << 3)));
        }
    } else {
#pragma unroll
        for (int mt = 0; mt < 4; ++mt) {
            int rowL = wr * 64 + mt * 16 + quad * 4;
#pragma unroll
            for (int r = 0; r < 4; ++r) {
                int rr = m0 + rowL + r;
                if (rr < n_e) {
                    int tok = list[(size_t)e * CAP + rr];
                    float g = gate[tok];
#pragma unroll
                    for (int nt = 0; nt < 4; ++nt) {
                        int col = n0 + wc * 64 + nt * 16 + l15;
                        float v = acc[mt][nt][r] + bias[(size_t)e * ND + col];
                        Out[(size_t)tok * CDIM + col] = v * g;
                    }
                }
            }
        }
    }
}

extern "C" void kernel_launch(void* const* d_in, const int* in_sizes, int n_in,
                              void* d_out, int out_size, void* d_ws, size_t ws_size,
                              hipStream_t stream)
{
    const float* x       = (const float*)d_in[0];
    const float* noise   = (const float*)d_in[1];
    const float* w_route = (const float*)d_in[2];
    const float* b_route = (const float*)d_in[3];
    const float* w_noise = (const float*)d_in[4];
    const float* b_noise = (const float*)d_in[5];
    const float* w1      = (const float*)d_in[6];
    const float* b1      = (const float*)d_in[7];
    const float* w2      = (const float*)d_in[8];
    const float* b2      = (const float*)d_in[9];
    float* out = (float*)d_out;

    char* ws = (char*)d_ws;
    size_t off = 0;
    auto alloc = [&](size_t bytes) {
        char* p = ws + off;
        off += (bytes + 255) & ~(size_t)255;
        return p;
    };
    int*   cnt  = (int*)alloc((size_t)E_NUM * CNT_PAD * sizeof(int));
    int*   list = (int*)alloc((size_t)E_NUM * CAP * sizeof(int));
    float* gate = (float*)alloc((size_t)NTOK * sizeof(float));
    u16*   W1t  = (u16*)alloc((size_t)E_NUM * DFF * CDIM * 2);
    u16*   W2t  = (u16*)alloc((size_t)E_NUM * CDIM * DFF * 2);

    u16* Xbf = (u16*)alloc((size_t)(NTOK + 1) * CDIM * 2);  // +1 zero dummy row
    size_t rows = NTOK + E_NUM * 128;  // packed-row bound
    u16* Hb = (u16*)alloc(rows * DFF * 2);

    hipMemsetAsync(cnt, 0, (size_t)E_NUM * CNT_PAD * sizeof(int), stream);
    hipMemsetAsync(Xbf + (size_t)NTOK * CDIM, 0, CDIM * 2, stream);  // dummy row

    routing_kernel<<<NTOK / RT_TOK, 256, 0, stream>>>(x, noise, w_route, b_route,
                                                      w_noise, b_noise, cnt, list, gate, Xbf);
    transpose_cvt_kernel<<<dim3(48, 12, 16), dim3(32, 8), 0, stream>>>(w1, W1t, w2, W2t);

    gemm_kernel<CDIM, DFF, true><<<dim3((DFF / 128) * 512), 256, 0, stream>>>(
        Xbf, W1t, b1, Hb, nullptr, cnt, list, nullptr);
    gemm_kernel<DFF, CDIM, false><<<dim3((CDIM / 128) * 512), 256, 0, stream>>>(
        Hb, W2t, b2, nullptr, out, cnt, list, gate);
}